// Round 6
// baseline (71.899 us; speedup 1.0000x reference)
//
#include <hip/hip_runtime.h>

#define D 256
#define W8 2048

// workspace float offsets
#define TCARD_OFF   0                 // 53*256  (pre-scaled by 1/7)
#define THERO_OFF   13568             // 9*256
#define TACT_OFF    15872             // 9*256
#define TNUMP_OFF   18176             // 10*256
#define WSC_OFF     20736             // 2*256 (transposed [k][d])  -- rows 0..1
#define WBET_OFF    21248             // 9*256                      -- rows 2..10
#define WACT_OFF    23552             // 8*256                      -- rows 11..18
#define WBL_OFF     25600             // 2*256                      -- rows 19..20
#define BPART_OFF   26112             // 4*256 bias partials
// NOTE: WSC..WBL are 21 contiguous rows — embed_kernel copies them as one slab.

typedef float nf4 __attribute__((ext_vector_type(4)));  // native vec for nontemporal store

__device__ __forceinline__ void f4acc(float4& a, const float4 b) {
    a.x += b.x; a.y += b.y; a.z += b.z; a.w += b.w;
}
__device__ __forceinline__ void f4fma(float4& a, float v, const float4 b) {
    a.x += v * b.x; a.y += v * b.y; a.z += v * b.z; a.w += v * b.w;
}

// -------- precompute: fold combine_W into tables & section weights --------

template <int NK>
__device__ void fuse_section(const float* __restrict__ combine_W, int wblk,
                             const float* __restrict__ sw,   // LDS [NK][D]
                             const float* __restrict__ sb,   // LDS [D]
                             float* __restrict__ dstT,       // ws [NK][D]
                             float* __restrict__ bpart,      // ws [D]
                             int d)
{
    float acc[NK];
#pragma unroll
    for (int k = 0; k < NK; ++k) acc[k] = 0.f;
    float accb = 0.f;
    const float* wrow = combine_W + (size_t)d * W8 + wblk * D;
    for (int dd = 0; dd < D; dd += 4) {
        float4 w = *(const float4*)(wrow + dd);
        accb += w.x * sb[dd] + w.y * sb[dd + 1] + w.z * sb[dd + 2] + w.w * sb[dd + 3];
#pragma unroll
        for (int k = 0; k < NK; ++k) {
            const float* s = sw + k * D + dd;
            acc[k] += w.x * s[0] + w.y * s[1] + w.z * s[2] + w.w * s[3];
        }
    }
#pragma unroll
    for (int k = 0; k < NK; ++k) dstT[k * D + d] = acc[k];
    bpart[d] = accb;
}

__global__ __launch_bounds__(256) void fuse_kernel(
    const float* __restrict__ combine_W,
    const float* __restrict__ card_t, const float* __restrict__ hero_t,
    const float* __restrict__ act_t,  const float* __restrict__ nump_t,
    const float* __restrict__ scalar_W, const float* __restrict__ scalar_b,
    const float* __restrict__ blind_W,  const float* __restrict__ blind_b,
    const float* __restrict__ bet_W,    const float* __restrict__ bet_b,
    const float* __restrict__ action_W, const float* __restrict__ action_b,
    float* __restrict__ ws)
{
    __shared__ float sh[10 * D];  // 10 KB
    const int blk = blockIdx.x;
    const int d = threadIdx.x;

    if (blk < 81) {
        // fused embedding-table rows: T[r,d] = sum_k Wblk[d,k] * table[r,k]
        const float* src; int wblk; float* dst; float scale;
        if (blk < 53)      { src = card_t + blk * D;        wblk = 0; dst = ws + TCARD_OFF + blk * D; scale = 1.0f / 7.0f; }
        else if (blk < 62) { src = hero_t + (blk - 53) * D; wblk = 1; dst = ws + THERO_OFF + (blk - 53) * D; scale = 1.0f; }
        else if (blk < 71) { src = act_t  + (blk - 62) * D; wblk = 2; dst = ws + TACT_OFF  + (blk - 62) * D; scale = 1.0f; }
        else               { src = nump_t + (blk - 71) * D; wblk = 6; dst = ws + TNUMP_OFF + (blk - 71) * D; scale = 1.0f; }
        sh[d] = src[d];
        __syncthreads();
        const float* wrow = combine_W + (size_t)d * W8 + wblk * D;
        float a0 = 0.f, a1 = 0.f, a2 = 0.f, a3 = 0.f;
#pragma unroll 8
        for (int k = 0; k < D; k += 4) {
            float4 w = *(const float4*)(wrow + k);
            a0 += w.x * sh[k];     a1 += w.y * sh[k + 1];
            a2 += w.z * sh[k + 2]; a3 += w.w * sh[k + 3];
        }
        dst[d] = ((a0 + a1) + (a2 + a3)) * scale;
    } else {
        // fused linear-section weights (stored transposed [k][d]) + bias partials
        const int sec = blk - 81;
        const float* secW; const float* secB; int nk, wblk; float* dstT;
        switch (sec) {
            case 0:  secW = scalar_W; secB = scalar_b; nk = 2; wblk = 3; dstT = ws + WSC_OFF;  break;
            case 1:  secW = bet_W;    secB = bet_b;    nk = 9; wblk = 4; dstT = ws + WBET_OFF; break;
            case 2:  secW = action_W; secB = action_b; nk = 8; wblk = 5; dstT = ws + WACT_OFF; break;
            default: secW = blind_W;  secB = blind_b;  nk = 2; wblk = 7; dstT = ws + WBL_OFF;  break;
        }
        for (int k = 0; k < nk; ++k) sh[k * D + d] = secW[d * nk + k];  // transpose into LDS
        sh[9 * D + d] = secB[d];
        __syncthreads();
        float* bpart = ws + BPART_OFF + sec * D;
        if (nk == 2)      fuse_section<2>(combine_W, wblk, sh, sh + 9 * D, dstT, bpart, d);
        else if (nk == 8) fuse_section<8>(combine_W, wblk, sh, sh + 9 * D, dstT, bpart, d);
        else              fuse_section<9>(combine_W, wblk, sh, sh + 9 * D, dstT, bpart, d);
    }
}

// -------- main: weights in 22.5 KB LDS; 4 tokens per wave iteration --------
// R5 analysis: 22 ds_read_b128/token = ~14 us of LDS issue. Batching 4 tokens
// per iteration reads each weight row ONCE and FMAs into 4 accumulators ->
// LDS issue /4, plus 4x independent gathers for latency hiding.

#define EMB_BLOCKS 1024
#define EMB_THREADS 256
#define EMB_WAVES (EMB_THREADS / 64)
#define WROWS 22   // 21 weight rows + 1 fused-bias row
#define TPW 4      // tokens per wave iteration

__global__ __launch_bounds__(EMB_THREADS) void embed_kernel(
    const int* __restrict__ cards,  const int* __restrict__ hero,
    const int* __restrict__ acting, const int* __restrict__ nump,
    const float* __restrict__ scalars, const float* __restrict__ blinds,
    const float* __restrict__ bets,    const float* __restrict__ action,
    const float* __restrict__ mask,    const float* __restrict__ combine_b,
    const float* __restrict__ ws, float* __restrict__ out, int ntok)
{
    __shared__ __align__(16) float wlds[WROWS * D];  // 22528 B

    const int tid = threadIdx.x;

    // rows 0..20: one contiguous slab ws[WSC_OFF .. WSC_OFF+21*256)
    {
        const float4* src = (const float4*)(ws + WSC_OFF);
        float4* dst = (float4*)wlds;
        for (int i = tid; i < 21 * (D / 4); i += EMB_THREADS) dst[i] = src[i];
        // row 21: fused bias = combine_b + 4 section-bias partials
        wlds[21 * D + tid] = combine_b[tid]
            + ws[BPART_OFF + 0 * D + tid] + ws[BPART_OFF + 1 * D + tid]
            + ws[BPART_OFF + 2 * D + tid] + ws[BPART_OFF + 3 * D + tid];
    }
    __syncthreads();

    const int lane = tid & 63;
    const int wave = tid >> 6;
    const int d0 = lane * 4;

    const float4 bias = *(const float4*)(wlds + 21 * D + d0);

    const int gw = blockIdx.x * EMB_WAVES + wave;
    const int nw = EMB_BLOCKS * EMB_WAVES;

    for (int t0 = gw * TPW; t0 < ntok; t0 += nw * TPW) {
        const int nt = (ntok - t0 < TPW) ? (ntok - t0) : TPW;

        float4 acc[TPW];
#pragma unroll
        for (int t = 0; t < TPW; ++t) acc[t] = bias;

        // gathers from L2-resident ws (independent across 4 tokens)
#pragma unroll
        for (int t = 0; t < TPW; ++t) {
            if (t >= nt) break;
            const int tok = t0 + t;
            const int* cp = cards + tok * 7;
#pragma unroll
            for (int j = 0; j < 7; ++j)
                f4acc(acc[t], *(const float4*)(ws + TCARD_OFF + cp[j] * D + d0));
            f4acc(acc[t], *(const float4*)(ws + THERO_OFF + hero[tok]   * D + d0));
            f4acc(acc[t], *(const float4*)(ws + TACT_OFF  + acting[tok] * D + d0));
            f4acc(acc[t], *(const float4*)(ws + TNUMP_OFF + nump[tok]   * D + d0));
        }

        // ---- sections: each LDS row read once, applied to TPW tokens ----
        {
            float2 fs[TPW];
#pragma unroll
            for (int t = 0; t < TPW; ++t)
                fs[t] = (t < nt) ? *(const float2*)(scalars + (t0 + t) * 2) : float2{0.f, 0.f};
            const float4 w0 = *(const float4*)(wlds + 0 * D + d0);
            const float4 w1 = *(const float4*)(wlds + 1 * D + d0);
#pragma unroll
            for (int t = 0; t < TPW; ++t) {
                f4fma(acc[t], fs[t].x, w0);
                f4fma(acc[t], fs[t].y, w1);
            }
        }
#pragma unroll
        for (int k = 0; k < 9; ++k) {
            const float4 wk = *(const float4*)(wlds + (2 + k) * D + d0);
#pragma unroll
            for (int t = 0; t < TPW; ++t)
                if (t < nt) f4fma(acc[t], bets[(t0 + t) * 9 + k], wk);
        }
        {
            float4 fa0[TPW], fa1[TPW];
#pragma unroll
            for (int t = 0; t < TPW; ++t) {
                if (t < nt) {
                    fa0[t] = *(const float4*)(action + (t0 + t) * 8);
                    fa1[t] = *(const float4*)(action + (t0 + t) * 8 + 4);
                } else {
                    fa0[t] = float4{0.f, 0.f, 0.f, 0.f};
                    fa1[t] = float4{0.f, 0.f, 0.f, 0.f};
                }
            }
            const float4 w11 = *(const float4*)(wlds + 11 * D + d0);
            const float4 w12 = *(const float4*)(wlds + 12 * D + d0);
            const float4 w13 = *(const float4*)(wlds + 13 * D + d0);
            const float4 w14 = *(const float4*)(wlds + 14 * D + d0);
#pragma unroll
            for (int t = 0; t < TPW; ++t) {
                f4fma(acc[t], fa0[t].x, w11); f4fma(acc[t], fa0[t].y, w12);
                f4fma(acc[t], fa0[t].z, w13); f4fma(acc[t], fa0[t].w, w14);
            }
            const float4 w15 = *(const float4*)(wlds + 15 * D + d0);
            const float4 w16 = *(const float4*)(wlds + 16 * D + d0);
            const float4 w17 = *(const float4*)(wlds + 17 * D + d0);
            const float4 w18 = *(const float4*)(wlds + 18 * D + d0);
#pragma unroll
            for (int t = 0; t < TPW; ++t) {
                f4fma(acc[t], fa1[t].x, w15); f4fma(acc[t], fa1[t].y, w16);
                f4fma(acc[t], fa1[t].z, w17); f4fma(acc[t], fa1[t].w, w18);
            }
        }
        {
            float2 fl[TPW];
#pragma unroll
            for (int t = 0; t < TPW; ++t)
                fl[t] = (t < nt) ? *(const float2*)(blinds + (t0 + t) * 2) : float2{0.f, 0.f};
            const float4 w19 = *(const float4*)(wlds + 19 * D + d0);
            const float4 w20 = *(const float4*)(wlds + 20 * D + d0);
#pragma unroll
            for (int t = 0; t < TPW; ++t) {
                f4fma(acc[t], fl[t].x, w19);
                f4fma(acc[t], fl[t].y, w20);
            }
        }

#pragma unroll
        for (int t = 0; t < TPW; ++t) {
            if (t >= nt) break;
            const int tok = t0 + t;
            const float m = mask[tok];
            nf4 o;
            o.x = acc[t].x * m; o.y = acc[t].y * m;
            o.z = acc[t].z * m; o.w = acc[t].w * m;
            __builtin_nontemporal_store(o, (nf4*)(out + (size_t)tok * D + d0));
        }
    }
}

extern "C" void kernel_launch(void* const* d_in, const int* in_sizes, int n_in,
                              void* d_out, int out_size, void* d_ws, size_t ws_size,
                              hipStream_t stream) {
    const int*   cards    = (const int*)d_in[0];
    const int*   hero     = (const int*)d_in[1];
    const int*   acting   = (const int*)d_in[2];
    const int*   nump     = (const int*)d_in[3];
    const float* scalars  = (const float*)d_in[4];
    const float* blinds   = (const float*)d_in[5];
    const float* bets     = (const float*)d_in[6];
    const float* action   = (const float*)d_in[7];
    const float* mask     = (const float*)d_in[8];
    const float* card_t   = (const float*)d_in[9];
    const float* hero_t   = (const float*)d_in[10];
    const float* act_t    = (const float*)d_in[11];
    const float* nump_t   = (const float*)d_in[12];
    const float* scalar_W = (const float*)d_in[13];
    const float* scalar_b = (const float*)d_in[14];
    const float* blind_W  = (const float*)d_in[15];
    const float* blind_b  = (const float*)d_in[16];
    const float* bet_W    = (const float*)d_in[17];
    const float* bet_b    = (const float*)d_in[18];
    const float* action_W = (const float*)d_in[19];
    const float* action_b = (const float*)d_in[20];
    const float* combine_W= (const float*)d_in[21];
    const float* combine_b= (const float*)d_in[22];

    float* ws  = (float*)d_ws;
    float* out = (float*)d_out;
    const int ntok = in_sizes[1];  // B*S (hero_pos flat count)

    hipLaunchKernelGGL(fuse_kernel, dim3(85), dim3(256), 0, stream,
                       combine_W, card_t, hero_t, act_t, nump_t,
                       scalar_W, scalar_b, blind_W, blind_b, bet_W, bet_b,
                       action_W, action_b, ws);
    hipLaunchKernelGGL(embed_kernel, dim3(EMB_BLOCKS), dim3(EMB_THREADS), 0, stream,
                       cards, hero, acting, nump, scalars, blinds, bets, action, mask,
                       combine_b, ws, out, ntok);
}

// Round 7
// 44.703 us; speedup vs baseline: 1.6083x; 1.6083x over previous
//
#include <hip/hip_runtime.h>

#define D 256
#define W8 2048

// workspace float offsets
#define TCARD_OFF   0                 // 53*256  (pre-scaled by 1/7)
#define THERO_OFF   13568             // 9*256
#define TACT_OFF    15872             // 9*256
#define TNUMP_OFF   18176             // 10*256
#define WSC_OFF     20736             // 2*256 (transposed [k][d])  -- rows 0..1
#define WBET_OFF    21248             // 9*256                      -- rows 2..10
#define WACT_OFF    23552             // 8*256                      -- rows 11..18
#define WBL_OFF     25600             // 2*256                      -- rows 19..20
#define BPART_OFF   26112             // 4*256 bias partials
// NOTE: WSC..WBL are 21 contiguous rows — embed_kernel copies them as one slab.

typedef float nf4 __attribute__((ext_vector_type(4)));               // native vec (nontemporal store)
typedef float f4a4 __attribute__((ext_vector_type(4), aligned(4)));  // under-aligned vec loads

__device__ __forceinline__ void f4acc(float4& a, const float4 b) {
    a.x += b.x; a.y += b.y; a.z += b.z; a.w += b.w;
}
__device__ __forceinline__ void f4fma(float4& a, float v, const float4 b) {
    a.x += v * b.x; a.y += v * b.y; a.z += v * b.z; a.w += v * b.w;
}

// -------- precompute: fold combine_W into tables & section weights --------

template <int NK>
__device__ void fuse_section(const float* __restrict__ combine_W, int wblk,
                             const float* __restrict__ sw,   // LDS [NK][D]
                             const float* __restrict__ sb,   // LDS [D]
                             float* __restrict__ dstT,       // ws [NK][D]
                             float* __restrict__ bpart,      // ws [D]
                             int d)
{
    float acc[NK];
#pragma unroll
    for (int k = 0; k < NK; ++k) acc[k] = 0.f;
    float accb = 0.f;
    const float* wrow = combine_W + (size_t)d * W8 + wblk * D;
    for (int dd = 0; dd < D; dd += 4) {
        float4 w = *(const float4*)(wrow + dd);
        accb += w.x * sb[dd] + w.y * sb[dd + 1] + w.z * sb[dd + 2] + w.w * sb[dd + 3];
#pragma unroll
        for (int k = 0; k < NK; ++k) {
            const float* s = sw + k * D + dd;
            acc[k] += w.x * s[0] + w.y * s[1] + w.z * s[2] + w.w * s[3];
        }
    }
#pragma unroll
    for (int k = 0; k < NK; ++k) dstT[k * D + d] = acc[k];
    bpart[d] = accb;
}

__global__ __launch_bounds__(256) void fuse_kernel(
    const float* __restrict__ combine_W,
    const float* __restrict__ card_t, const float* __restrict__ hero_t,
    const float* __restrict__ act_t,  const float* __restrict__ nump_t,
    const float* __restrict__ scalar_W, const float* __restrict__ scalar_b,
    const float* __restrict__ blind_W,  const float* __restrict__ blind_b,
    const float* __restrict__ bet_W,    const float* __restrict__ bet_b,
    const float* __restrict__ action_W, const float* __restrict__ action_b,
    float* __restrict__ ws)
{
    __shared__ float sh[10 * D];  // 10 KB
    const int blk = blockIdx.x;
    const int d = threadIdx.x;

    if (blk < 81) {
        // fused embedding-table rows: T[r,d] = sum_k Wblk[d,k] * table[r,k]
        const float* src; int wblk; float* dst; float scale;
        if (blk < 53)      { src = card_t + blk * D;        wblk = 0; dst = ws + TCARD_OFF + blk * D; scale = 1.0f / 7.0f; }
        else if (blk < 62) { src = hero_t + (blk - 53) * D; wblk = 1; dst = ws + THERO_OFF + (blk - 53) * D; scale = 1.0f; }
        else if (blk < 71) { src = act_t  + (blk - 62) * D; wblk = 2; dst = ws + TACT_OFF  + (blk - 62) * D; scale = 1.0f; }
        else               { src = nump_t + (blk - 71) * D; wblk = 6; dst = ws + TNUMP_OFF + (blk - 71) * D; scale = 1.0f; }
        sh[d] = src[d];
        __syncthreads();
        const float* wrow = combine_W + (size_t)d * W8 + wblk * D;
        float a0 = 0.f, a1 = 0.f, a2 = 0.f, a3 = 0.f;
#pragma unroll 8
        for (int k = 0; k < D; k += 4) {
            float4 w = *(const float4*)(wrow + k);
            a0 += w.x * sh[k];     a1 += w.y * sh[k + 1];
            a2 += w.z * sh[k + 2]; a3 += w.w * sh[k + 3];
        }
        dst[d] = ((a0 + a1) + (a2 + a3)) * scale;
    } else {
        // fused linear-section weights (stored transposed [k][d]) + bias partials
        const int sec = blk - 81;
        const float* secW; const float* secB; int nk, wblk; float* dstT;
        switch (sec) {
            case 0:  secW = scalar_W; secB = scalar_b; nk = 2; wblk = 3; dstT = ws + WSC_OFF;  break;
            case 1:  secW = bet_W;    secB = bet_b;    nk = 9; wblk = 4; dstT = ws + WBET_OFF; break;
            case 2:  secW = action_W; secB = action_b; nk = 8; wblk = 5; dstT = ws + WACT_OFF; break;
            default: secW = blind_W;  secB = blind_b;  nk = 2; wblk = 7; dstT = ws + WBL_OFF;  break;
        }
        for (int k = 0; k < nk; ++k) sh[k * D + d] = secW[d * nk + k];  // transpose into LDS
        sh[9 * D + d] = secB[d];
        __syncthreads();
        float* bpart = ws + BPART_OFF + sec * D;
        if (nk == 2)      fuse_section<2>(combine_W, wblk, sh, sh + 9 * D, dstT, bpart, d);
        else if (nk == 8) fuse_section<8>(combine_W, wblk, sh, sh + 9 * D, dstT, bpart, d);
        else              fuse_section<9>(combine_W, wblk, sh, sh + 9 * D, dstT, bpart, d);
    }
}

// -------- main: weights in 22.5 KB LDS; 2 tokens per wave (explicit A/B) ----
// R6 lesson: k-outer feature loads (bets[(t0+t)*9+k]) were scattered scalar
// L2 loads serialized against the LDS-FMA sweep. Here ALL features load
// contiguously up-front (mergeable dwordx4), then the 21-row LDS sweep is
// pure ds_read_b128 + register FMA, each row amortized over 2 tokens.

#define EMB_BLOCKS 2048
#define EMB_THREADS 256
#define EMB_WAVES (EMB_THREADS / 64)
#define WROWS 22   // 21 weight rows + 1 fused-bias row

__global__ __launch_bounds__(EMB_THREADS) void embed_kernel(
    const int* __restrict__ cards,  const int* __restrict__ hero,
    const int* __restrict__ acting, const int* __restrict__ nump,
    const float* __restrict__ scalars, const float* __restrict__ blinds,
    const float* __restrict__ bets,    const float* __restrict__ action,
    const float* __restrict__ mask,    const float* __restrict__ combine_b,
    const float* __restrict__ ws, float* __restrict__ out, int ntok)
{
    __shared__ __align__(16) float wlds[WROWS * D];  // 22528 B

    const int tid = threadIdx.x;

    // rows 0..20: one contiguous slab ws[WSC_OFF .. WSC_OFF+21*256)
    {
        const float4* src = (const float4*)(ws + WSC_OFF);
        float4* dst = (float4*)wlds;
        for (int i = tid; i < 21 * (D / 4); i += EMB_THREADS) dst[i] = src[i];
        // row 21: fused bias = combine_b + 4 section-bias partials
        wlds[21 * D + tid] = combine_b[tid]
            + ws[BPART_OFF + 0 * D + tid] + ws[BPART_OFF + 1 * D + tid]
            + ws[BPART_OFF + 2 * D + tid] + ws[BPART_OFF + 3 * D + tid];
    }
    __syncthreads();

    const int lane = tid & 63;
    const int wave = tid >> 6;
    const int d0 = lane * 4;

    const float4 bias = *(const float4*)(wlds + 21 * D + d0);

    const int gw = blockIdx.x * EMB_WAVES + wave;
    const int nw = EMB_BLOCKS * EMB_WAVES;
    const int npair = ntok >> 1;

    for (int p = gw; p < npair; p += nw) {
        const int tokA = 2 * p;
        const int tokB = 2 * p + 1;

        // ---- contiguous feature loads, both tokens, up front ----
        const f4a4 btA0 = *(const f4a4*)(bets + (size_t)tokA * 9);
        const f4a4 btA1 = *(const f4a4*)(bets + (size_t)tokA * 9 + 4);
        const float btA8 = bets[(size_t)tokA * 9 + 8];
        const f4a4 btB0 = *(const f4a4*)(bets + (size_t)tokB * 9);
        const f4a4 btB1 = *(const f4a4*)(bets + (size_t)tokB * 9 + 4);
        const float btB8 = bets[(size_t)tokB * 9 + 8];

        const float4 aA0 = *(const float4*)(action + (size_t)tokA * 8);
        const float4 aA1 = *(const float4*)(action + (size_t)tokA * 8 + 4);
        const float4 aB0 = *(const float4*)(action + (size_t)tokB * 8);
        const float4 aB1 = *(const float4*)(action + (size_t)tokB * 8 + 4);

        const float2 sA = *(const float2*)(scalars + (size_t)tokA * 2);
        const float2 sB = *(const float2*)(scalars + (size_t)tokB * 2);
        const float2 lA = *(const float2*)(blinds + (size_t)tokA * 2);
        const float2 lB = *(const float2*)(blinds + (size_t)tokB * 2);
        const float mA = mask[tokA];
        const float mB = mask[tokB];

        // ---- gathers from L2-resident ws ----
        float4 accA = bias;
        float4 accB = bias;
        const int* cpA = cards + (size_t)tokA * 7;
        const int* cpB = cards + (size_t)tokB * 7;
#pragma unroll
        for (int j = 0; j < 7; ++j)
            f4acc(accA, *(const float4*)(ws + TCARD_OFF + cpA[j] * D + d0));
#pragma unroll
        for (int j = 0; j < 7; ++j)
            f4acc(accB, *(const float4*)(ws + TCARD_OFF + cpB[j] * D + d0));
        f4acc(accA, *(const float4*)(ws + THERO_OFF + hero[tokA]   * D + d0));
        f4acc(accA, *(const float4*)(ws + TACT_OFF  + acting[tokA] * D + d0));
        f4acc(accA, *(const float4*)(ws + TNUMP_OFF + nump[tokA]   * D + d0));
        f4acc(accB, *(const float4*)(ws + THERO_OFF + hero[tokB]   * D + d0));
        f4acc(accB, *(const float4*)(ws + TACT_OFF  + acting[tokB] * D + d0));
        f4acc(accB, *(const float4*)(ws + TNUMP_OFF + nump[tokB]   * D + d0));

        // ---- 21-row LDS sweep: each row read once, 2 FMAs ----
        {
            const float4 w0 = *(const float4*)(wlds + 0 * D + d0);
            f4fma(accA, sA.x, w0); f4fma(accB, sB.x, w0);
            const float4 w1 = *(const float4*)(wlds + 1 * D + d0);
            f4fma(accA, sA.y, w1); f4fma(accB, sB.y, w1);

            const float4 w2 = *(const float4*)(wlds + 2 * D + d0);
            f4fma(accA, btA0.x, w2); f4fma(accB, btB0.x, w2);
            const float4 w3 = *(const float4*)(wlds + 3 * D + d0);
            f4fma(accA, btA0.y, w3); f4fma(accB, btB0.y, w3);
            const float4 w4 = *(const float4*)(wlds + 4 * D + d0);
            f4fma(accA, btA0.z, w4); f4fma(accB, btB0.z, w4);
            const float4 w5 = *(const float4*)(wlds + 5 * D + d0);
            f4fma(accA, btA0.w, w5); f4fma(accB, btB0.w, w5);
            const float4 w6 = *(const float4*)(wlds + 6 * D + d0);
            f4fma(accA, btA1.x, w6); f4fma(accB, btB1.x, w6);
            const float4 w7 = *(const float4*)(wlds + 7 * D + d0);
            f4fma(accA, btA1.y, w7); f4fma(accB, btB1.y, w7);
            const float4 w8 = *(const float4*)(wlds + 8 * D + d0);
            f4fma(accA, btA1.z, w8); f4fma(accB, btB1.z, w8);
            const float4 w9 = *(const float4*)(wlds + 9 * D + d0);
            f4fma(accA, btA1.w, w9); f4fma(accB, btB1.w, w9);
            const float4 w10 = *(const float4*)(wlds + 10 * D + d0);
            f4fma(accA, btA8, w10); f4fma(accB, btB8, w10);

            const float4 w11 = *(const float4*)(wlds + 11 * D + d0);
            f4fma(accA, aA0.x, w11); f4fma(accB, aB0.x, w11);
            const float4 w12 = *(const float4*)(wlds + 12 * D + d0);
            f4fma(accA, aA0.y, w12); f4fma(accB, aB0.y, w12);
            const float4 w13 = *(const float4*)(wlds + 13 * D + d0);
            f4fma(accA, aA0.z, w13); f4fma(accB, aB0.z, w13);
            const float4 w14 = *(const float4*)(wlds + 14 * D + d0);
            f4fma(accA, aA0.w, w14); f4fma(accB, aB0.w, w14);
            const float4 w15 = *(const float4*)(wlds + 15 * D + d0);
            f4fma(accA, aA1.x, w15); f4fma(accB, aB1.x, w15);
            const float4 w16 = *(const float4*)(wlds + 16 * D + d0);
            f4fma(accA, aA1.y, w16); f4fma(accB, aB1.y, w16);
            const float4 w17 = *(const float4*)(wlds + 17 * D + d0);
            f4fma(accA, aA1.z, w17); f4fma(accB, aB1.z, w17);
            const float4 w18 = *(const float4*)(wlds + 18 * D + d0);
            f4fma(accA, aA1.w, w18); f4fma(accB, aB1.w, w18);

            const float4 w19 = *(const float4*)(wlds + 19 * D + d0);
            f4fma(accA, lA.x, w19); f4fma(accB, lB.x, w19);
            const float4 w20 = *(const float4*)(wlds + 20 * D + d0);
            f4fma(accA, lA.y, w20); f4fma(accB, lB.y, w20);
        }

        nf4 oA, oB;
        oA.x = accA.x * mA; oA.y = accA.y * mA; oA.z = accA.z * mA; oA.w = accA.w * mA;
        oB.x = accB.x * mB; oB.y = accB.y * mB; oB.z = accB.z * mB; oB.w = accB.w * mB;
        __builtin_nontemporal_store(oA, (nf4*)(out + (size_t)tokA * D + d0));
        __builtin_nontemporal_store(oB, (nf4*)(out + (size_t)tokB * D + d0));
    }

    // odd-ntok tail: one token, handled by global wave 0
    if ((ntok & 1) && gw == 0) {
        const int tok = ntok - 1;
        float4 acc = bias;
        const int* cp = cards + (size_t)tok * 7;
#pragma unroll
        for (int j = 0; j < 7; ++j)
            f4acc(acc, *(const float4*)(ws + TCARD_OFF + cp[j] * D + d0));
        f4acc(acc, *(const float4*)(ws + THERO_OFF + hero[tok]   * D + d0));
        f4acc(acc, *(const float4*)(ws + TACT_OFF  + acting[tok] * D + d0));
        f4acc(acc, *(const float4*)(ws + TNUMP_OFF + nump[tok]   * D + d0));
        const float2 fs = *(const float2*)(scalars + (size_t)tok * 2);
        f4fma(acc, fs.x, *(const float4*)(wlds + 0 * D + d0));
        f4fma(acc, fs.y, *(const float4*)(wlds + 1 * D + d0));
#pragma unroll
        for (int k = 0; k < 9; ++k)
            f4fma(acc, bets[(size_t)tok * 9 + k], *(const float4*)(wlds + (2 + k) * D + d0));
        const f4a4 fa0 = *(const f4a4*)(action + (size_t)tok * 8);
        const f4a4 fa1 = *(const f4a4*)(action + (size_t)tok * 8 + 4);
        f4fma(acc, fa0.x, *(const float4*)(wlds + 11 * D + d0));
        f4fma(acc, fa0.y, *(const float4*)(wlds + 12 * D + d0));
        f4fma(acc, fa0.z, *(const float4*)(wlds + 13 * D + d0));
        f4fma(acc, fa0.w, *(const float4*)(wlds + 14 * D + d0));
        f4fma(acc, fa1.x, *(const float4*)(wlds + 15 * D + d0));
        f4fma(acc, fa1.y, *(const float4*)(wlds + 16 * D + d0));
        f4fma(acc, fa1.z, *(const float4*)(wlds + 17 * D + d0));
        f4fma(acc, fa1.w, *(const float4*)(wlds + 18 * D + d0));
        const float2 fl = *(const float2*)(blinds + (size_t)tok * 2);
        f4fma(acc, fl.x, *(const float4*)(wlds + 19 * D + d0));
        f4fma(acc, fl.y, *(const float4*)(wlds + 20 * D + d0));
        const float m = mask[tok];
        nf4 o;
        o.x = acc.x * m; o.y = acc.y * m; o.z = acc.z * m; o.w = acc.w * m;
        __builtin_nontemporal_store(o, (nf4*)(out + (size_t)tok * D + d0));
    }
}

extern "C" void kernel_launch(void* const* d_in, const int* in_sizes, int n_in,
                              void* d_out, int out_size, void* d_ws, size_t ws_size,
                              hipStream_t stream) {
    const int*   cards    = (const int*)d_in[0];
    const int*   hero     = (const int*)d_in[1];
    const int*   acting   = (const int*)d_in[2];
    const int*   nump     = (const int*)d_in[3];
    const float* scalars  = (const float*)d_in[4];
    const float* blinds   = (const float*)d_in[5];
    const float* bets     = (const float*)d_in[6];
    const float* action   = (const float*)d_in[7];
    const float* mask     = (const float*)d_in[8];
    const float* card_t   = (const float*)d_in[9];
    const float* hero_t   = (const float*)d_in[10];
    const float* act_t    = (const float*)d_in[11];
    const float* nump_t   = (const float*)d_in[12];
    const float* scalar_W = (const float*)d_in[13];
    const float* scalar_b = (const float*)d_in[14];
    const float* blind_W  = (const float*)d_in[15];
    const float* blind_b  = (const float*)d_in[16];
    const float* bet_W    = (const float*)d_in[17];
    const float* bet_b    = (const float*)d_in[18];
    const float* action_W = (const float*)d_in[19];
    const float* action_b = (const float*)d_in[20];
    const float* combine_W= (const float*)d_in[21];
    const float* combine_b= (const float*)d_in[22];

    float* ws  = (float*)d_ws;
    float* out = (float*)d_out;
    const int ntok = in_sizes[1];  // B*S (hero_pos flat count)

    hipLaunchKernelGGL(fuse_kernel, dim3(85), dim3(256), 0, stream,
                       combine_W, card_t, hero_t, act_t, nump_t,
                       scalar_W, scalar_b, blind_W, blind_b, bet_W, bet_b,
                       action_W, action_b, ws);
    hipLaunchKernelGGL(embed_kernel, dim3(EMB_BLOCKS), dim3(EMB_THREADS), 0, stream,
                       cards, hero, acting, nump, scalars, blinds, bets, action, mask,
                       combine_b, ws, out, ntok);
}